// Round 2
// baseline (443.076 us; speedup 1.0000x reference)
//
#include <hip/hip_runtime.h>

// Problem constants (fixed by setup_inputs): B=32, N=2048, d=64.
constexpr int Bv = 32;
constexpr int N  = 2048;   // power of 2 -> all index math is shifts
constexpr int D  = 64;

// Kernel 1: mask[b*N + n] = (||nodes[b,n] - nodes[b,nn[b]]||^2 < 0.25)
__global__ void mask_kernel(const float* __restrict__ nodes,
                            const int* __restrict__ num_nodes,
                            unsigned char* __restrict__ mask) {
    int idx = blockIdx.x * blockDim.x + threadIdx.x;   // [0, Bv*N)
    int b = idx >> 11;          // / N
    int n = idx & (N - 1);
    int nn = num_nodes[b];      // harness passes integer inputs as int32
    const float4* p = (const float4*)(nodes + ((size_t)b * N + n)  * D);
    const float4* q = (const float4*)(nodes + ((size_t)b * N + nn) * D);
    float acc = 0.f;
#pragma unroll
    for (int k = 0; k < D / 4; ++k) {
        float4 a = p[k], c = q[k];
        float dx = a.x - c.x, dy = a.y - c.y, dz = a.z - c.z, dw = a.w - c.w;
        acc = fmaf(dx, dx, acc);
        acc = fmaf(dy, dy, acc);
        acc = fmaf(dz, dz, acc);
        acc = fmaf(dw, dw, acc);
    }
    mask[idx] = (acc < 0.25f) ? 1 : 0;
}

// Kernel 2: out[b,i,j] = ((i==nn && mask[j]) || (j==nn && mask[i])) ? 1 : adj_in[b,i,j]
// Vectorized: one float4 (4 consecutive j) per iteration, grid-stride.
__global__ void adj_kernel(const float* __restrict__ adj_in,
                           const int* __restrict__ num_nodes,
                           const unsigned char* __restrict__ mask,
                           float* __restrict__ adj_out) {
    constexpr long long TOT = (long long)Bv * N * (N / 4);   // vec4 elements
    const long long stride = (long long)gridDim.x * blockDim.x;
    for (long long idx = (long long)blockIdx.x * blockDim.x + threadIdx.x;
         idx < TOT; idx += stride) {
        int b   = (int)(idx >> 20);                 // / (N*N/4) = 2^20
        int rem = (int)(idx & ((1 << 20) - 1));
        int i   = rem >> 9;                         // / (N/4) = 512
        int j0  = (rem & 511) << 2;

        float4 v = ((const float4*)adj_in)[idx];

        int nn = num_nodes[b];                      // L1-cached broadcast
        if (i == nn) {
            const unsigned char* mb = mask + (b << 11) + j0;
            if (mb[0]) v.x = 1.f;
            if (mb[1]) v.y = 1.f;
            if (mb[2]) v.z = 1.f;
            if (mb[3]) v.w = 1.f;
        }
        if (nn >= j0 && nn < j0 + 4) {
            if (mask[(b << 11) + i]) {
                float* vf = &v.x;
                vf[nn - j0] = 1.f;
            }
        }
        ((float4*)adj_out)[idx] = v;
    }
}

extern "C" void kernel_launch(void* const* d_in, const int* in_sizes, int n_in,
                              void* d_out, int out_size, void* d_ws, size_t ws_size,
                              hipStream_t stream) {
    // Input order per setup_inputs(): nodes, adj_mats, edge_weights, num_nodes, B
    const float* nodes = (const float*)d_in[0];
    const float* adj   = (const float*)d_in[1];
    const float* ew    = (const float*)d_in[2];
    const int*   nn    = (const int*)d_in[3];     // harness: integer -> int32
    float* out = (float*)d_out;
    unsigned char* mask = (unsigned char*)d_ws;   // Bv*N bytes, rewritten each call

    const size_t nnn = (size_t)Bv * N * N;        // elements per output tensor

    // 1. distance mask (tiny)
    mask_kernel<<<(Bv * N) / 256, 256, 0, stream>>>(nodes, nn, mask);

    // 2. adj copy + row/col fixup (BW-bound half 1)
    adj_kernel<<<2048, 256, 0, stream>>>(adj, nn, mask, out);

    // 3. edge_weights passthrough (BW-bound half 2)
    hipMemcpyAsync(out + nnn, ew, nnn * sizeof(float),
                   hipMemcpyDeviceToDevice, stream);
}

// Round 4
// 435.191 us; speedup vs baseline: 1.0181x; 1.0181x over previous
//
#include <hip/hip_runtime.h>

// Problem constants (fixed by setup_inputs): B=32, N=2048, d=64.
constexpr int Bv = 32;
constexpr int N  = 2048;   // power of 2 -> all index math is shifts
constexpr int D  = 64;

// clang-native vector type: required by __builtin_nontemporal_load/store
// (HIP's float4 is a class and is rejected by the builtin).
typedef float f32x4 __attribute__((ext_vector_type(4)));

// Kernel 1: mask[b*N + n] = (||nodes[b,n] - nodes[b,nn[b]]||^2 < 0.25)
__global__ void mask_kernel(const float* __restrict__ nodes,
                            const int* __restrict__ num_nodes,
                            unsigned char* __restrict__ mask) {
    int idx = blockIdx.x * blockDim.x + threadIdx.x;   // [0, Bv*N)
    int b = idx >> 11;          // / N
    int n = idx & (N - 1);
    int nn = num_nodes[b];      // harness passes integer inputs as int32
    const f32x4* p = (const f32x4*)(nodes + ((size_t)b * N + n)  * D);
    const f32x4* q = (const f32x4*)(nodes + ((size_t)b * N + nn) * D);
    float acc = 0.f;
#pragma unroll
    for (int k = 0; k < D / 4; ++k) {
        f32x4 a = p[k], c = q[k];
        f32x4 df = a - c;
        acc = fmaf(df[0], df[0], acc);
        acc = fmaf(df[1], df[1], acc);
        acc = fmaf(df[2], df[2], acc);
        acc = fmaf(df[3], df[3], acc);
    }
    mask[idx] = (acc < 0.25f) ? 1 : 0;
}

// Kernel 2 (fused): one grid-stride pass over BOTH output halves in vec4 units.
//   idx <  TOT : out[idx] = fixup(adj_in[idx])   (adj half)
//   idx >= TOT : out[idx] = ew[idx - TOT]        (edge_weights passthrough)
// Streams use nontemporal load/store (1 GB each way, no reuse — skip caches).
__global__ void fused_kernel(const float* __restrict__ adj_in,
                             const float* __restrict__ ew,
                             const int* __restrict__ num_nodes,
                             const unsigned char* __restrict__ mask,
                             float* __restrict__ out) {
    constexpr long long TOT  = (long long)Bv * N * (N / 4);  // 2^25 vec4 elems
    constexpr long long TOT2 = 2 * TOT;
    const long long stride = (long long)gridDim.x * blockDim.x;
    const f32x4* adj4 = (const f32x4*)adj_in;
    const f32x4* ew4  = (const f32x4*)ew;
    f32x4*       out4 = (f32x4*)out;

    for (long long idx = (long long)blockIdx.x * blockDim.x + threadIdx.x;
         idx < TOT2; idx += stride) {
        if (idx < TOT) {
            f32x4 v = __builtin_nontemporal_load(adj4 + idx);

            int b   = (int)(idx >> 20);                 // / (N*N/4) = 2^20
            int rem = (int)(idx & ((1 << 20) - 1));
            int i   = rem >> 9;                         // / (N/4) = 512
            int j0  = (rem & 511) << 2;

            int nn = num_nodes[b];                      // L1-cached broadcast
            if (i == nn) {
                const unsigned char* mb = mask + (b << 11) + j0;
                if (mb[0]) v[0] = 1.f;
                if (mb[1]) v[1] = 1.f;
                if (mb[2]) v[2] = 1.f;
                if (mb[3]) v[3] = 1.f;
            }
            if (nn >= j0 && nn < j0 + 4) {
                if (mask[(b << 11) + i]) {
                    v[nn - j0] = 1.f;
                }
            }
            __builtin_nontemporal_store(v, out4 + idx);
        } else {
            f32x4 v = __builtin_nontemporal_load(ew4 + (idx - TOT));
            __builtin_nontemporal_store(v, out4 + idx);
        }
    }
}

extern "C" void kernel_launch(void* const* d_in, const int* in_sizes, int n_in,
                              void* d_out, int out_size, void* d_ws, size_t ws_size,
                              hipStream_t stream) {
    // Input order per setup_inputs(): nodes, adj_mats, edge_weights, num_nodes, B
    const float* nodes = (const float*)d_in[0];
    const float* adj   = (const float*)d_in[1];
    const float* ew    = (const float*)d_in[2];
    const int*   nn    = (const int*)d_in[3];     // harness: integer -> int32
    float* out = (float*)d_out;
    unsigned char* mask = (unsigned char*)d_ws;   // Bv*N bytes, rewritten each call

    // 1. distance mask (tiny)
    mask_kernel<<<(Bv * N) / 256, 256, 0, stream>>>(nodes, nn, mask);

    // 2. fused adj fixup-copy + edge_weights copy (single BW-bound pass)
    fused_kernel<<<2048, 256, 0, stream>>>(adj, ew, nn, mask, out);
}